// Round 4
// baseline (398.004 us; speedup 1.0000x reference)
//
#include <hip/hip_runtime.h>
#include <hip/hip_bf16.h>

// Problem: B=32, L=1024, F=1024, H=1024, D=1024 — inputs fp32, OUTPUT fp32.
//   h1 = feat@W1 + b1; h2 = hidden@W2 + b2; att = tanh(h1 + h2[:,None,:])
//   score = att@Wp; w = softmax_L(score); out[b][f] = sum_l w[b][l]*feat[b][l][f]
//
// R12: all LDS-DMA schedules plateaued at ~1800cy/tile (vmcnt(0) drain of
//   just-issued global_load_lds at every barrier). This version has NO LDS-DMA:
//   - B frags read straight from L2-resident w1t (2MB) into regs, in-tile lead.
//   - A reg-staged depth-2 from fp32 feat with FUSED cvt (kills prep-cvt pass
//     + featb entirely); ds_write swizzled; all waits are counted dataflow.
//   - 128x128 tile, BK=32, 4 waves, 17.5KB LDS, 3 blocks/CU for stall overlap.

typedef __attribute__((ext_vector_type(8))) __bf16 bf16x8;
typedef __attribute__((ext_vector_type(4))) float f32x4;

static __device__ __forceinline__ ushort f2bf(float x) {  // RNE fp32->bf16
  unsigned u = __float_as_uint(x);
  return (ushort)((u + 0x7fffu + ((u >> 16) & 1u)) >> 16);
}

static __device__ __forceinline__ bf16x8 cvt8(float4 lo, float4 hi) {
  __hip_bfloat162 c0 = __float22bfloat162_rn({lo.x, lo.y});
  __hip_bfloat162 c1 = __float22bfloat162_rn({lo.z, lo.w});
  __hip_bfloat162 c2 = __float22bfloat162_rn({hi.x, hi.y});
  __hip_bfloat162 c3 = __float22bfloat162_rn({hi.z, hi.w});
  union { int4 i; bf16x8 v; } u;
  u.i.x = *(int*)&c0; u.i.y = *(int*)&c1; u.i.z = *(int*)&c2; u.i.w = *(int*)&c3;
  return u.v;
}

// fast tanh: 1 - 2/(e^{2x}+1). exp(+inf)->inf gives 1; exp(-inf)->0 gives -1.
static __device__ __forceinline__ float tanh_fast(float x) {
  float e = __expf(2.f * x);
  return 1.f - 2.f / (e + 1.f);
}

// ---------- prep: 256 W1-transpose blocks | +1024 h2 blocks ----------
__global__ __launch_bounds__(256) void prep_kernel(
    const float* __restrict__ W1, ushort* __restrict__ w1t,
    const float* __restrict__ hidden, const float* __restrict__ W2,
    const float* __restrict__ b2, float* __restrict__ h2p) {
  __shared__ float smem[64 * 65];
  const int bx = blockIdx.x, tid = threadIdx.x;
  if (bx < 256) {
    // W1 [F][D] fp32 -> W1T [D][F] bf16, 64x64 tiles
    const int tc = bx & 15, tr = bx >> 4;
    float (*tt)[65] = (float(*)[65])smem;
    const int r = tid >> 4, c4 = (tid & 15) * 4;
#pragma unroll
    for (int p = 0; p < 4; ++p) {
      const int rr = p * 16 + r;
      float4 v = *(const float4*)(W1 + (size_t)(tr * 64 + rr) * 1024 + tc * 64 + c4);
      tt[rr][c4] = v.x; tt[rr][c4 + 1] = v.y; tt[rr][c4 + 2] = v.z; tt[rr][c4 + 3] = v.w;
    }
    __syncthreads();
    const int cc = tid >> 3, r8 = (tid & 7) * 8;
#pragma unroll
    for (int p = 0; p < 2; ++p) {
      const int c = p * 32 + cc;
      ushort tmp[8];
#pragma unroll
      for (int j = 0; j < 8; ++j) tmp[j] = f2bf(tt[r8 + j][c]);
      *(int4*)(w1t + (size_t)(tc * 64 + c) * 1024 + tr * 64 + r8) = *(int4*)tmp;
    }
  } else {
    // h2p[z][b][d] = hidden[b][128z:+128] @ W2[...,d] (+b2 at z==0)
    const int t = bx - 256;  // 0..1023
    const int dblk = t & 3, b = (t >> 2) & 31, z = t >> 7;
    const int d = dblk * 256 + tid;
    const int k0 = z * 128;
    float* h = smem;
    if (tid < 128) h[tid] = hidden[b * 1024 + k0 + tid];
    __syncthreads();
    float acc = (z == 0) ? b2[d] : 0.f;
#pragma unroll 8
    for (int k = 0; k < 128; ++k)
      acc += h[k] * W2[(size_t)(k0 + k) * 1024 + d];
    h2p[z * 32768 + b * 1024 + d] = acc;
  }
}

// ======== GEMM+score: 128x128 tile, BK=32, 256 thr / 4 waves, no LDS-DMA ======
// A: fp32 feat -> regs (depth-2 prefetch) -> fused cvt -> swizzled ds_write.
// B: bf16x8 frags straight from L2-resident w1t (no LDS).
// LDS A layout [2][128][32]: 16B chunk c of row r stored at slot c^((r>>1)&3)
// (2-way bank alias = free). One __syncthreads per K-tile; no vmem drains
// because every global load is consumed before the barrier.

#define MFMA_ROW(AF, I)                                                        \
  acc[I][0] = __builtin_amdgcn_mfma_f32_16x16x32_bf16(AF, bf0, acc[I][0], 0, 0, 0); \
  acc[I][1] = __builtin_amdgcn_mfma_f32_16x16x32_bf16(AF, bf1, acc[I][1], 0, 0, 0); \
  acc[I][2] = __builtin_amdgcn_mfma_f32_16x16x32_bf16(AF, bf2, acc[I][2], 0, 0, 0); \
  acc[I][3] = __builtin_amdgcn_mfma_f32_16x16x32_bf16(AF, bf3, acc[I][3], 0, 0, 0);

#define TILE_STEP(T, CUR, NXT, AVIN, AVOUT) {                                  \
    /* B frags tile T (L2) */                                                  \
    bf16x8 bf0 = *(const bf16x8*)(bb + (T) * 32);                              \
    bf16x8 bf1 = *(const bf16x8*)(bb + 16384 + (T) * 32);                      \
    bf16x8 bf2 = *(const bf16x8*)(bb + 32768 + (T) * 32);                      \
    bf16x8 bf3 = *(const bf16x8*)(bb + 49152 + (T) * 32);                      \
    /* A(T+2) fp32 prefetch */                                                 \
    if ((T) + 2 < 32) {                                                        \
      const float* ap_ = feat + (size_t)(row0 + ar) * 1024 + ((T) + 2) * 32 + akof; \
      AVOUT[0] = *(const float4*)(ap_);                                        \
      AVOUT[1] = *(const float4*)(ap_ + 4);                                    \
      AVOUT[2] = *(const float4*)(ap_ + 8);                                    \
      AVOUT[3] = *(const float4*)(ap_ + 12);                                   \
    }                                                                          \
    /* A frags from LDS[CUR] */                                                \
    bf16x8 af0 = *(const bf16x8*)&ldsA[CUR][wm * 64 + lrow][cswz8];            \
    bf16x8 af1 = *(const bf16x8*)&ldsA[CUR][wm * 64 + 16 + lrow][cswz8];       \
    bf16x8 af2 = *(const bf16x8*)&ldsA[CUR][wm * 64 + 32 + lrow][cswz8];       \
    bf16x8 af3 = *(const bf16x8*)&ldsA[CUR][wm * 64 + 48 + lrow][cswz8];       \
    MFMA_ROW(af0, 0); MFMA_ROW(af1, 1); MFMA_ROW(af2, 2); MFMA_ROW(af3, 3);    \
    /* stage A(T+1) -> LDS[NXT] (fused cvt) */                                 \
    if ((T) + 1 < 32) {                                                        \
      union { bf16x8 v; int4 i; } w0_, w1_;                                    \
      w0_.v = cvt8(AVIN[0], AVIN[1]);                                          \
      w1_.v = cvt8(AVIN[2], AVIN[3]);                                          \
      *(int4*)&ldsA[NXT][ar][awz0] = w0_.i;                                    \
      *(int4*)&ldsA[NXT][ar][awz1] = w1_.i;                                    \
    }                                                                          \
    __syncthreads();                                                           \
  }

__global__ __launch_bounds__(256, 3) void gemm_score_kernel(
    const float* __restrict__ feat,    // fp32 [32768][1024]
    const ushort* __restrict__ w1t,    // bf16 [1024][1024] (W1 transposed)
    const float* __restrict__ b1, const float* __restrict__ h2p,
    const float* __restrict__ wp, float* __restrict__ score_p) {
  __shared__ ushort ldsA[2][128][32];  // 16 KB
  __shared__ float sred[2][64];
  __shared__ float hbl[128], wpl[128];

  const int tid = threadIdx.x;
  const int row0 = blockIdx.x * 128;
  const int col0 = blockIdx.y * 128;
  const int b = blockIdx.x >> 3;

  const int wave = tid >> 6, lane = tid & 63;
  const int wm = wave & 1, wn = wave >> 1;
  const int lrow = lane & 15, quad = lane >> 4;
  const int cswz8 = (quad ^ ((lrow >> 1) & 3)) * 8;  // frag-read chunk (bytes/2)

  // preloop: hb (b1 + sum of h2 partials) and wp slices for this col block
  if (tid < 128) {
    const int d = col0 + tid;
    float hv = b1[d];
#pragma unroll
    for (int p = 0; p < 8; ++p) hv += h2p[p * 32768 + b * 1024 + d];
    hbl[tid] = hv;
  } else {
    wpl[tid - 128] = wp[col0 + tid - 128];
  }

  // A staging role: thread t -> row ar=t>>1, k-slice akof=(t&1)*16 (16 fp32)
  const int ar = tid >> 1;
  const int akof = (tid & 1) * 16;
  const int xr = (ar >> 1) & 3;
  const int awz0 = ((2 * (tid & 1) + 0) ^ xr) * 8;  // ushort index of 16B chunk
  const int awz1 = ((2 * (tid & 1) + 1) ^ xr) * 8;

  // B frag base: wave wn covers cols wn*64 + j*16 + lrow; k-chunk quad*8
  const ushort* bb = w1t + (size_t)(col0 + wn * 64 + lrow) * 1024 + quad * 8;

  f32x4 acc[4][4] = {};
  float4 avA[4], avB[4];

  // prologue: stage A(0) -> LDS[0]; prefetch A(1) fp32 -> avA
  {
    const float* ap_ = feat + (size_t)(row0 + ar) * 1024 + akof;
    float4 v0 = *(const float4*)(ap_);
    float4 v1 = *(const float4*)(ap_ + 4);
    float4 v2 = *(const float4*)(ap_ + 8);
    float4 v3 = *(const float4*)(ap_ + 12);
    union { bf16x8 v; int4 i; } w0_, w1_;
    w0_.v = cvt8(v0, v1);
    w1_.v = cvt8(v2, v3);
    *(int4*)&ldsA[0][ar][awz0] = w0_.i;
    *(int4*)&ldsA[0][ar][awz1] = w1_.i;
    const float* ap1_ = ap_ + 32;
    avA[0] = *(const float4*)(ap1_);
    avA[1] = *(const float4*)(ap1_ + 4);
    avA[2] = *(const float4*)(ap1_ + 8);
    avA[3] = *(const float4*)(ap1_ + 12);
  }
  __syncthreads();

  for (int t = 0; t < 32; t += 2) {
    TILE_STEP(t, 0, 1, avA, avB);
    TILE_STEP(t + 1, 1, 0, avB, avA);
  }

  // ---- epilogue: score partial per row over this 128-col block ----
  float hbv[4], wpv[4];
#pragma unroll
  for (int j = 0; j < 4; ++j) {
    const int idx = wn * 64 + j * 16 + lrow;
    hbv[j] = hbl[idx];
    wpv[j] = wpl[idx];
  }
  float rsum[4][4];
#pragma unroll
  for (int i = 0; i < 4; ++i) {
#pragma unroll
    for (int r = 0; r < 4; ++r) {
      float s = 0.f;
#pragma unroll
      for (int j = 0; j < 4; ++j)
        s += tanh_fast(acc[i][j][r] + hbv[j]) * wpv[j];
      s += __shfl_xor(s, 8);
      s += __shfl_xor(s, 4);
      s += __shfl_xor(s, 2);
      s += __shfl_xor(s, 1);
      rsum[i][r] = s;
    }
  }
  if (wn == 1 && lrow == 0) {
#pragma unroll
    for (int i = 0; i < 4; ++i)
#pragma unroll
      for (int r = 0; r < 4; ++r)
        sred[wm][i * 16 + quad * 4 + r] = rsum[i][r];
  }
  __syncthreads();
  if (wn == 0 && lrow == 0) {
#pragma unroll
    for (int i = 0; i < 4; ++i)
#pragma unroll
      for (int r = 0; r < 4; ++r) {
        const int ro = wm * 64 + i * 16 + quad * 4 + r;
        score_p[(size_t)blockIdx.y * 32768 + row0 + ro] =
            rsum[i][r] + sred[wm][ro & 63];
      }
  }
}

// -------- softmax over L per b (sums 8 partials); also zeroes out[b][:] --------
__global__ __launch_bounds__(256) void softmax_kernel(
    const float* __restrict__ score_p, float* __restrict__ w,
    float* __restrict__ out) {
  const int b = blockIdx.x, tid = threadIdx.x;
  const int lane = tid & 63, wv = tid >> 6;
  __shared__ float sm[4], ss[4];
  float v[4];
  float mx = -1e30f;
#pragma unroll
  for (int i = 0; i < 4; ++i) {
    const int idx = b * 1024 + i * 256 + tid;
    out[idx] = 0.f;  // d_out poisoned; context atomicAdds later
    float s = 0.f;
#pragma unroll
    for (int p = 0; p < 8; ++p) s += score_p[p * 32768 + idx];
    v[i] = s;
    mx = fmaxf(mx, s);
  }
#pragma unroll
  for (int off = 32; off; off >>= 1) mx = fmaxf(mx, __shfl_xor(mx, off));
  if (lane == 0) sm[wv] = mx;
  __syncthreads();
  mx = fmaxf(fmaxf(sm[0], sm[1]), fmaxf(sm[2], sm[3]));
  float sum = 0.f;
#pragma unroll
  for (int i = 0; i < 4; ++i) {
    v[i] = __expf(v[i] - mx);
    sum += v[i];
  }
#pragma unroll
  for (int off = 32; off; off >>= 1) sum += __shfl_xor(sum, off);
  if (lane == 0) ss[wv] = sum;
  __syncthreads();
  const float inv = 1.f / (ss[0] + ss[1] + ss[2] + ss[3]);
#pragma unroll
  for (int i = 0; i < 4; ++i) w[b * 1024 + i * 256 + tid] = v[i] * inv;
}

// -------- out[b][f] += sum_{l in 64-chunk} w[b][l]*feat[b][l][f] (fp32) --------
__global__ __launch_bounds__(256) void context_kernel(
    const float* __restrict__ w, const float* __restrict__ feat,
    float* __restrict__ out) {
  const int b = blockIdx.y;
  const int l0 = blockIdx.x * 64;
  const int f0 = threadIdx.x * 4;
  __shared__ float wl[64];
  if (threadIdx.x < 64) wl[threadIdx.x] = w[b * 1024 + l0 + threadIdx.x];
  __syncthreads();
  const float* fb = feat + (size_t)b * 1048576 + (size_t)l0 * 1024 + f0;
  float a0 = 0.f, a1 = 0.f, a2 = 0.f, a3 = 0.f;
#pragma unroll 8
  for (int l = 0; l < 64; ++l) {
    float4 v = *(const float4*)(fb + (size_t)l * 1024);
    const float wv = wl[l];
    a0 += wv * v.x;
    a1 += wv * v.y;
    a2 += wv * v.z;
    a3 += wv * v.w;
  }
  float* dst = out + b * 1024 + f0;
  atomicAdd(dst + 0, a0);
  atomicAdd(dst + 1, a1);
  atomicAdd(dst + 2, a2);
  atomicAdd(dst + 3, a3);
}

extern "C" void kernel_launch(void* const* d_in, const int* in_sizes, int n_in,
                              void* d_out, int out_size, void* d_ws, size_t ws_size,
                              hipStream_t stream) {
  const float* feat   = (const float*)d_in[0];
  const float* hidden = (const float*)d_in[1];
  const float* W1     = (const float*)d_in[2];
  const float* b1     = (const float*)d_in[3];
  const float* W2     = (const float*)d_in[4];
  const float* b2     = (const float*)d_in[5];
  const float* Wp     = (const float*)d_in[6];
  float* out = (float*)d_out;

  char* ws = (char*)d_ws;
  ushort* w1t    = (ushort*)ws;                  // 2 MB
  float* score_p = (float*)(ws + 2097152);       // 1 MB [8][32768]
  float* h2p     = (float*)(ws + 3145728);       // 1 MB [8][32768]
  float* wts     = (float*)(ws + 4194304);       // 128 KB

  prep_kernel<<<1280, 256, 0, stream>>>(W1, w1t, hidden, W2, b2, h2p);
  gemm_score_kernel<<<dim3(256, 8), 256, 0, stream>>>(feat, w1t, b1, h2p, Wp,
                                                      score_p);
  softmax_kernel<<<32, 256, 0, stream>>>(score_p, wts, out);
  context_kernel<<<dim3(16, 32), 256, 0, stream>>>(wts, feat, out);
}

// Round 5
// 358.695 us; speedup vs baseline: 1.1096x; 1.1096x over previous
//
#include <hip/hip_runtime.h>
#include <hip/hip_bf16.h>

// Problem: B=32, L=1024, F=1024, H=1024, D=1024 — inputs fp32, OUTPUT fp32.
//   h1 = feat@W1 + b1; h2 = hidden@W2 + b2; att = tanh(h1 + h2[:,None,:])
//   score = att@Wp; w = softmax_L(score); out[b][f] = sum_l w[b][l]*feat[b][l][f]
//
// R13: R12's 467MB FETCH = 8x fp32 feat re-read (col-split grid). Fix geometry:
//   one block = 64-row strip x ALL 1024 cols (512 blocks, 8 waves, wave-tile
//   64x128). feat read ONCE (fused fp32->bf16 cvt, reg-staged depth-2); B frags
//   reg-prefetched 1 tile ahead from L2-resident w1t; LDS only 8KB A-dbuf.
//   Loop uses raw s_barrier + lgkmcnt(0) (no __syncthreads, nothing to drain:
//   all vmem is lane-private reg dataflow). 1280 cy/tile between barriers >
//   HBM latency -> robust even to conservative drains. score partials 4 -> 1.
//   prep-cvt pass and featb (64MB ws) deleted; ws 4.3MB shrinks poison-fill.

typedef __attribute__((ext_vector_type(8))) __bf16 bf16x8;
typedef __attribute__((ext_vector_type(4))) float f32x4;

static __device__ __forceinline__ ushort f2bf(float x) {  // RNE fp32->bf16
  unsigned u = __float_as_uint(x);
  return (ushort)((u + 0x7fffu + ((u >> 16) & 1u)) >> 16);
}

static __device__ __forceinline__ int2 cvt4(float4 v) {  // 4 fp32 -> 4 bf16 (RNE)
  __hip_bfloat162 c0 = __float22bfloat162_rn({v.x, v.y});
  __hip_bfloat162 c1 = __float22bfloat162_rn({v.z, v.w});
  int2 r;
  r.x = *(int*)&c0;
  r.y = *(int*)&c1;
  return r;
}

// fast tanh: 1 - 2/(e^{2x}+1). exp(+inf)->inf gives 1; exp(-inf)->0 gives -1.
static __device__ __forceinline__ float tanh_fast(float x) {
  float e = __expf(2.f * x);
  return 1.f - 2.f / (e + 1.f);
}

// ---------- prep: 256 W1-transpose blocks | +1024 h2 blocks ----------
__global__ __launch_bounds__(256) void prep_kernel(
    const float* __restrict__ W1, ushort* __restrict__ w1t,
    const float* __restrict__ hidden, const float* __restrict__ W2,
    const float* __restrict__ b2, float* __restrict__ h2p) {
  __shared__ float smem[64 * 65];
  const int bx = blockIdx.x, tid = threadIdx.x;
  if (bx < 256) {
    // W1 [F][D] fp32 -> W1T [D][F] bf16, 64x64 tiles
    const int tc = bx & 15, tr = bx >> 4;
    float (*tt)[65] = (float(*)[65])smem;
    const int r = tid >> 4, c4 = (tid & 15) * 4;
#pragma unroll
    for (int p = 0; p < 4; ++p) {
      const int rr = p * 16 + r;
      float4 v = *(const float4*)(W1 + (size_t)(tr * 64 + rr) * 1024 + tc * 64 + c4);
      tt[rr][c4] = v.x; tt[rr][c4 + 1] = v.y; tt[rr][c4 + 2] = v.z; tt[rr][c4 + 3] = v.w;
    }
    __syncthreads();
    const int cc = tid >> 3, r8 = (tid & 7) * 8;
#pragma unroll
    for (int p = 0; p < 2; ++p) {
      const int c = p * 32 + cc;
      ushort tmp[8];
#pragma unroll
      for (int j = 0; j < 8; ++j) tmp[j] = f2bf(tt[r8 + j][c]);
      *(int4*)(w1t + (size_t)(tc * 64 + c) * 1024 + tr * 64 + r8) = *(int4*)tmp;
    }
  } else {
    // h2p[z][b][d] = hidden[b][128z:+128] @ W2[...,d] (+b2 at z==0)
    const int t = bx - 256;  // 0..1023
    const int dblk = t & 3, b = (t >> 2) & 31, z = t >> 7;
    const int d = dblk * 256 + tid;
    const int k0 = z * 128;
    float* h = smem;
    if (tid < 128) h[tid] = hidden[b * 1024 + k0 + tid];
    __syncthreads();
    float acc = (z == 0) ? b2[d] : 0.f;
#pragma unroll 8
    for (int k = 0; k < 128; ++k)
      acc += h[k] * W2[(size_t)(k0 + k) * 1024 + d];
    h2p[z * 32768 + b * 1024 + d] = acc;
  }
}

// ======== GEMM+score: 64-row strip x 1024 cols, BK=32, 512 thr / 8 waves ======
// A: fp32 feat -> regs (2-slot, 2-tile cover) -> fused cvt -> swizzled ds_write
//    into 8KB dbuf LDS. B: bf16x8 frags from L2-resident w1t, 1 tile ahead.
// LDS A [2][64][32]: 16B chunk c of row r at slot c^((r>>1)&3) (2-way = free).
// One raw s_barrier + lgkmcnt(0) per K-tile; vmem is lane-private (no drains).

__global__ __launch_bounds__(512, 2) void gemm_score_kernel(
    const float* __restrict__ feat,    // fp32 [32768][1024]
    const ushort* __restrict__ w1t,    // bf16 [1024][1024] (W1 transposed)
    const float* __restrict__ b1, const float* __restrict__ h2p,
    const float* __restrict__ wp, float* __restrict__ score) {
  __shared__ ushort ldsA[2][64][32];  // 8 KB
  __shared__ float hbl[1024], wpl[1024];
  __shared__ float sred[7][64];

  const int tid = threadIdx.x;
  const int row0 = blockIdx.x * 64;
  const int b = blockIdx.x >> 4;
  const int wave = tid >> 6, lane = tid & 63;
  const int lrow = lane & 15, quad = lane >> 4;

  // preloop: hb = b1 + sum_z h2p over all 1024 cols; wp
  {
    const int d = tid * 2;
    float2 hv = *(const float2*)(b1 + d);
#pragma unroll
    for (int p = 0; p < 8; ++p) {
      float2 hp = *(const float2*)(h2p + p * 32768 + b * 1024 + d);
      hv.x += hp.x;
      hv.y += hp.y;
    }
    *(float2*)(hbl + d) = hv;
    *(float2*)(wpl + d) = *(const float2*)(wp + d);
  }

  // A staging role: thread -> row ar=tid>>3, k-offset (tid&7)*4 fp32 (16B)
  const int ar = tid >> 3;
  const int asw = ((((tid & 7) >> 1) ^ ((ar >> 1) & 3)) * 8 + (tid & 1) * 4);
  const float* aptr = feat + (size_t)(row0 + ar) * 1024 + (tid & 7) * 4;

  // A frag read: row i*16+lrow, swizzled 16B chunk
  const int acs = (quad ^ ((lrow >> 1) & 3)) * 8;

  // B frag bases: wave covers cols wave*128 + j*16 + lrow; k-chunk quad*8
  const ushort* bb[8];
#pragma unroll
  for (int j = 0; j < 8; ++j)
    bb[j] = w1t + (size_t)(wave * 128 + j * 16 + lrow) * 1024 + quad * 8;

  f32x4 acc[4][8] = {};
  float4 avv[2];
  bf16x8 bB[2][8];

  // prologue: stage tile0 direct; prefetch A fp32 tiles 1,2; B frags tile0
  {
    float4 v0 = *(const float4*)(aptr);
    *(int2*)&ldsA[0][ar][asw] = cvt4(v0);
    avv[1] = *(const float4*)(aptr + 32);  // tile1 -> slot (1&1)=1
    avv[0] = *(const float4*)(aptr + 64);  // tile2 -> slot (2&1)=0
#pragma unroll
    for (int j = 0; j < 8; ++j) bB[0][j] = *(const bf16x8*)(bb[j]);
  }
  asm volatile("s_waitcnt lgkmcnt(0)");
  __builtin_amdgcn_sched_barrier(0);
  __builtin_amdgcn_s_barrier();
  __builtin_amdgcn_sched_barrier(0);

#pragma unroll
  for (int t = 0; t < 32; ++t) {
    const int cur = t & 1, nxt = cur ^ 1;
    // A frags from LDS[cur]
    bf16x8 af[4];
#pragma unroll
    for (int i = 0; i < 4; ++i)
      af[i] = *(const bf16x8*)&ldsA[cur][i * 16 + lrow][acs];
    // issue B frag loads for t+1 (L2, ~1 tile cover)
    if (t + 1 < 32) {
#pragma unroll
      for (int j = 0; j < 8; ++j)
        bB[nxt][j] = *(const bf16x8*)(bb[j] + (t + 1) * 32);
    }
    // stage A(t+1): cvt regs (loaded at t-1, 2-tile cover) -> LDS[nxt];
    // then refill freed slot with A fp32 for t+3
    if (t + 1 < 32)
      *(int2*)&ldsA[nxt][ar][asw] = cvt4(avv[(t + 1) & 1]);
    if (t + 3 < 32)
      avv[(t + 1) & 1] = *(const float4*)(aptr + (t + 3) * 32);
    // MFMA 4x8
    __builtin_amdgcn_s_setprio(1);
#pragma unroll
    for (int i = 0; i < 4; ++i)
#pragma unroll
      for (int j = 0; j < 8; ++j)
        acc[i][j] = __builtin_amdgcn_mfma_f32_16x16x32_bf16(
            af[i], bB[cur][j], acc[i][j], 0, 0, 0);
    __builtin_amdgcn_s_setprio(0);
    // publish ds_write, tile boundary (raw barrier: no vmem drain)
    __builtin_amdgcn_sched_barrier(0);
    asm volatile("s_waitcnt lgkmcnt(0)");
    __builtin_amdgcn_sched_barrier(0);
    __builtin_amdgcn_s_barrier();
    __builtin_amdgcn_sched_barrier(0);
  }

  // ---- epilogue: score[row] = sum_d tanh(acc + hb[d]) * wp[d] over ALL d ----
  float hbv[8], wpv[8];
#pragma unroll
  for (int j = 0; j < 8; ++j) {
    const int c = wave * 128 + j * 16 + lrow;
    hbv[j] = hbl[c];
    wpv[j] = wpl[c];
  }
  float rsum[4][4];
#pragma unroll
  for (int i = 0; i < 4; ++i) {
#pragma unroll
    for (int r = 0; r < 4; ++r) {
      float s = 0.f;
#pragma unroll
      for (int j = 0; j < 8; ++j)
        s += tanh_fast(acc[i][j][r] + hbv[j]) * wpv[j];
      s += __shfl_xor(s, 8);
      s += __shfl_xor(s, 4);
      s += __shfl_xor(s, 2);
      s += __shfl_xor(s, 1);
      rsum[i][r] = s;  // row = i*16 + quad*4 + r (cols of this wave summed)
    }
  }
  if (wave != 0 && lrow == 0) {
#pragma unroll
    for (int i = 0; i < 4; ++i)
#pragma unroll
      for (int r = 0; r < 4; ++r)
        sred[wave - 1][i * 16 + quad * 4 + r] = rsum[i][r];
  }
  __syncthreads();
  if (wave == 0 && lrow == 0) {
#pragma unroll
    for (int i = 0; i < 4; ++i)
#pragma unroll
      for (int r = 0; r < 4; ++r) {
        const int ro = i * 16 + quad * 4 + r;
        float s = rsum[i][r];
#pragma unroll
        for (int w = 0; w < 7; ++w) s += sred[w][ro];
        score[row0 + ro] = s;
      }
  }
}

// -------- softmax over L per b; also zeroes out[b][:] --------
__global__ __launch_bounds__(256) void softmax_kernel(
    const float* __restrict__ score, float* __restrict__ w,
    float* __restrict__ out) {
  const int b = blockIdx.x, tid = threadIdx.x;
  const int lane = tid & 63, wv = tid >> 6;
  __shared__ float sm[4], ss[4];
  float v[4];
  float mx = -1e30f;
#pragma unroll
  for (int i = 0; i < 4; ++i) {
    const int idx = b * 1024 + i * 256 + tid;
    out[idx] = 0.f;  // d_out poisoned; context atomicAdds later
    v[i] = score[idx];
    mx = fmaxf(mx, v[i]);
  }
#pragma unroll
  for (int off = 32; off; off >>= 1) mx = fmaxf(mx, __shfl_xor(mx, off));
  if (lane == 0) sm[wv] = mx;
  __syncthreads();
  mx = fmaxf(fmaxf(sm[0], sm[1]), fmaxf(sm[2], sm[3]));
  float sum = 0.f;
#pragma unroll
  for (int i = 0; i < 4; ++i) {
    v[i] = __expf(v[i] - mx);
    sum += v[i];
  }
#pragma unroll
  for (int off = 32; off; off >>= 1) sum += __shfl_xor(sum, off);
  if (lane == 0) ss[wv] = sum;
  __syncthreads();
  const float inv = 1.f / (ss[0] + ss[1] + ss[2] + ss[3]);
#pragma unroll
  for (int i = 0; i < 4; ++i) w[b * 1024 + i * 256 + tid] = v[i] * inv;
}

// -------- out[b][f] += sum_{l in 64-chunk} w[b][l]*feat[b][l][f] (fp32) --------
__global__ __launch_bounds__(256) void context_kernel(
    const float* __restrict__ w, const float* __restrict__ feat,
    float* __restrict__ out) {
  const int b = blockIdx.y;
  const int l0 = blockIdx.x * 64;
  const int f0 = threadIdx.x * 4;
  __shared__ float wl[64];
  if (threadIdx.x < 64) wl[threadIdx.x] = w[b * 1024 + l0 + threadIdx.x];
  __syncthreads();
  const float* fb = feat + (size_t)b * 1048576 + (size_t)l0 * 1024 + f0;
  float a0 = 0.f, a1 = 0.f, a2 = 0.f, a3 = 0.f;
#pragma unroll 8
  for (int l = 0; l < 64; ++l) {
    float4 v = *(const float4*)(fb + (size_t)l * 1024);
    const float wv = wl[l];
    a0 += wv * v.x;
    a1 += wv * v.y;
    a2 += wv * v.z;
    a3 += wv * v.w;
  }
  float* dst = out + b * 1024 + f0;
  atomicAdd(dst + 0, a0);
  atomicAdd(dst + 1, a1);
  atomicAdd(dst + 2, a2);
  atomicAdd(dst + 3, a3);
}

extern "C" void kernel_launch(void* const* d_in, const int* in_sizes, int n_in,
                              void* d_out, int out_size, void* d_ws, size_t ws_size,
                              hipStream_t stream) {
  const float* feat   = (const float*)d_in[0];
  const float* hidden = (const float*)d_in[1];
  const float* W1     = (const float*)d_in[2];
  const float* b1     = (const float*)d_in[3];
  const float* W2     = (const float*)d_in[4];
  const float* b2     = (const float*)d_in[5];
  const float* Wp     = (const float*)d_in[6];
  float* out = (float*)d_out;

  char* ws = (char*)d_ws;
  ushort* w1t   = (ushort*)ws;              // 2 MB
  float* score  = (float*)(ws + 2097152);   // 128 KB [32768]
  float* h2p    = (float*)(ws + 3145728);   // 1 MB [8][32768]
  float* wts    = (float*)(ws + 4194304);   // 128 KB

  prep_kernel<<<1280, 256, 0, stream>>>(W1, w1t, hidden, W2, b2, h2p);
  gemm_score_kernel<<<512, 512, 0, stream>>>(feat, w1t, b1, h2p, Wp, score);
  softmax_kernel<<<32, 256, 0, stream>>>(score, wts, out);
  context_kernel<<<dim3(16, 32), 256, 0, stream>>>(wts, feat, out);
}

// Round 6
// 324.338 us; speedup vs baseline: 1.2271x; 1.1059x over previous
//
#include <hip/hip_runtime.h>
#include <hip/hip_bf16.h>

// Problem: B=32, L=1024, F=1024, H=1024, D=1024 — inputs fp32, OUTPUT fp32.
//   h1 = feat@W1 + b1; h2 = hidden@W2 + b2; att = tanh(h1 + h2[:,None,:])
//   score = att@Wp; w = softmax_L(score); out[b][f] = sum_l w[b][l]*feat[b][l][f]
//
// R14 = R11 schedule + R13's fused cvt, minus their mistakes:
//   - B staged via global_load_lds from L2-resident w1t (amortized across waves;
//     R13's B-from-global was a 16x per-CU L2 amplification -> 178us).
//   - A reg-staged from fp32 feat with fused f32->bf16 cvt (no prep-cvt pass,
//     no featb): loads for tile t+3 issued at t (2-tile+ cover > HBM latency).
//   - grid (4 colblk, 256 rowblk), colblk fastest: 4 col-blocks of a row-strip
//     are dispatch-adjacent -> feat window ~64MB fits L3 -> feat ~once from HBM.
//   - raw s_barrier + counted vmcnt(4) per tile (drain B-DMA only, keep A
//     prefetches in flight); sched_barrier(0) pins only the sync points.

typedef __attribute__((ext_vector_type(8))) __bf16 bf16x8;
typedef __attribute__((ext_vector_type(4))) float f32x4;

static __device__ __forceinline__ ushort f2bf(float x) {  // RNE fp32->bf16
  unsigned u = __float_as_uint(x);
  return (ushort)((u + 0x7fffu + ((u >> 16) & 1u)) >> 16);
}

typedef __attribute__((address_space(1))) void gbl_t;
typedef __attribute__((address_space(3))) void lds_t;
static __device__ __forceinline__ void gl_lds16(const void* g, void* l) {
  __builtin_amdgcn_global_load_lds((gbl_t*)g, (lds_t*)l, 16, 0, 0);
}

static __device__ __forceinline__ int2 cvt4(float4 v) {  // 4 fp32 -> 4 bf16 (RNE)
  __hip_bfloat162 c0 = __float22bfloat162_rn({v.x, v.y});
  __hip_bfloat162 c1 = __float22bfloat162_rn({v.z, v.w});
  int2 r;
  r.x = *(int*)&c0;
  r.y = *(int*)&c1;
  return r;
}

// fast tanh: 1 - 2/(e^{2x}+1). exp(+inf)->inf gives 1; exp(-inf)->0 gives -1.
static __device__ __forceinline__ float tanh_fast(float x) {
  float e = __expf(2.f * x);
  return 1.f - 2.f / (e + 1.f);
}

// ---------- prep: 256 W1-transpose blocks | +1024 h2 blocks ----------
__global__ __launch_bounds__(256) void prep_kernel(
    const float* __restrict__ W1, ushort* __restrict__ w1t,
    const float* __restrict__ hidden, const float* __restrict__ W2,
    const float* __restrict__ b2, float* __restrict__ h2p) {
  __shared__ float smem[64 * 65];
  const int bx = blockIdx.x, tid = threadIdx.x;
  if (bx < 256) {
    // W1 [F][D] fp32 -> W1T [D][F] bf16, 64x64 tiles
    const int tc = bx & 15, tr = bx >> 4;
    float (*tt)[65] = (float(*)[65])smem;
    const int r = tid >> 4, c4 = (tid & 15) * 4;
#pragma unroll
    for (int p = 0; p < 4; ++p) {
      const int rr = p * 16 + r;
      float4 v = *(const float4*)(W1 + (size_t)(tr * 64 + rr) * 1024 + tc * 64 + c4);
      tt[rr][c4] = v.x; tt[rr][c4 + 1] = v.y; tt[rr][c4 + 2] = v.z; tt[rr][c4 + 3] = v.w;
    }
    __syncthreads();
    const int cc = tid >> 3, r8 = (tid & 7) * 8;
#pragma unroll
    for (int p = 0; p < 2; ++p) {
      const int c = p * 32 + cc;
      ushort tmp[8];
#pragma unroll
      for (int j = 0; j < 8; ++j) tmp[j] = f2bf(tt[r8 + j][c]);
      *(int4*)(w1t + (size_t)(tc * 64 + c) * 1024 + tr * 64 + r8) = *(int4*)tmp;
    }
  } else {
    // h2p[z][b][d] = hidden[b][128z:+128] @ W2[...,d] (+b2 at z==0)
    const int t = bx - 256;  // 0..1023
    const int dblk = t & 3, b = (t >> 2) & 31, z = t >> 7;
    const int d = dblk * 256 + tid;
    const int k0 = z * 128;
    float* h = smem;
    if (tid < 128) h[tid] = hidden[b * 1024 + k0 + tid];
    __syncthreads();
    float acc = (z == 0) ? b2[d] : 0.f;
#pragma unroll 8
    for (int k = 0; k < 128; ++k)
      acc += h[k] * W2[(size_t)(k0 + k) * 1024 + d];
    h2p[z * 32768 + b * 1024 + d] = acc;
  }
}

// ======== GEMM+score: 128x256 tile, BK=32, 256 thr / 4 waves, 2 blk/CU ========
// LDS: A[2][128][32] bf16 (16KB, reg-staged w/ fused cvt, swizzled ds_write),
//      B[2][256][32] bf16 (32KB, gl_lds DMA, linear dest + pre-swizzled src).
// Swizzle (both operands): 16B chunk g of row r lives at slot g ^ ((r>>1)&3).
// Wave-tile 128x64: acc[8][4] f32x4. Per tile: raw s_barrier with counted
// vmcnt (B-DMA drained, A-prefetch loads for t+3 stay in flight).

#define STAGE_B(T, BUF) {                                                      \
    const int ko_ = (T) * 32;                                                  \
    gl_lds16(w1t + b_go + ko_,          (char*)ldsB + (BUF) * 16384 + lB);     \
    gl_lds16(w1t + b_go + 65536 + ko_,  (char*)ldsB + (BUF) * 16384 + lB + 4096); \
    gl_lds16(w1t + b_go + 131072 + ko_, (char*)ldsB + (BUF) * 16384 + lB + 8192); \
    gl_lds16(w1t + b_go + 196608 + ko_, (char*)ldsB + (BUF) * 16384 + lB + 12288); }

__global__ __launch_bounds__(256, 2) void gemm_score_kernel(
    const float* __restrict__ feat,    // fp32 [32768][1024]
    const ushort* __restrict__ w1t,    // bf16 [1024][1024] (W1 transposed)
    const float* __restrict__ b1, const float* __restrict__ h2p,
    const float* __restrict__ wp, float* __restrict__ score_p) {
  __shared__ ushort ldsA[2][128][32];  // 16 KB
  __shared__ ushort ldsB[2][256][32];  // 32 KB
  __shared__ float hbl[256], wpl[256];
  __shared__ float sred[3][128];

  const int tid = threadIdx.x;
  const int col0 = blockIdx.x * 256;   // x = col-block (fastest) -> L3 window
  const int row0 = blockIdx.y * 128;
  const int b = blockIdx.y >> 3;
  const int wave = tid >> 6, lane = tid & 63;
  const int lrow = lane & 15, quad = lane >> 4;
  const int acs = (quad ^ ((lrow >> 1) & 3)) * 8;  // frag-read chunk (ushorts)

  // preloop: hb (b1 + sum of h2 partials) and wp for this 256-col block
  {
    const int d = col0 + tid;
    float hv = b1[d];
#pragma unroll
    for (int p = 0; p < 8; ++p) hv += h2p[p * 32768 + b * 1024 + d];
    hbl[tid] = hv;
    wpl[tid] = wp[d];
  }

  // B staging: slot s=(wave*64+lane)+256p -> (row r=s>>2, chunk c=s&3);
  // source chunk q = c ^ ((r>>1)&3) (pre-swizzled src, linear DMA dest).
  int b_go, lB;
  {
    const int s = wave * 64 + lane;
    const int r = s >> 2, c = s & 3;
    const int q = c ^ ((r >> 1) & 3);
    b_go = (col0 + r) * 1024 + q * 8;
    lB = (wave * 64) * 16;  // lane*16 added by LDS-DMA hardware
  }

  // A staging: thread -> rows arow+32p (p=0..3), k-word (tid&7)*4 (16B seg;
  // lanes 0..7 cover one row contiguously -> 128B segments, coalesced).
  const int arow = tid >> 3;             // 0..31
  const int akq = (tid & 7) >> 1;        // global 16B-chunk 0..3
  const int xr = (arow >> 1) & 3;        // same for arow+32p (bit5 untouched)
  const int awz = ((akq ^ xr) * 8) + (tid & 1) * 4;  // ushort offset in row
  const float* aptrA = feat + (size_t)(row0 + arow) * 1024 + (tid & 7) * 4;

  f32x4 acc[8][4] = {};
  float4 avv[2][4];

  // ---- prologue: B-DMA tile0; A tile0 direct cvt-stage; prefetch A t1,t2 ----
  STAGE_B(0, 0);
  __builtin_amdgcn_sched_barrier(0);
#pragma unroll
  for (int p = 0; p < 4; ++p) {
    float4 v = *(const float4*)(aptrA + (size_t)p * 32768);
    *(int2*)&ldsA[0][arow + 32 * p][awz] = cvt4(v);
  }
#pragma unroll
  for (int p = 0; p < 4; ++p)
    avv[1][p] = *(const float4*)(aptrA + (size_t)p * 32768 + 32);
#pragma unroll
  for (int p = 0; p < 4; ++p)
    avv[0][p] = *(const float4*)(aptrA + (size_t)p * 32768 + 64);
  asm volatile("s_waitcnt vmcnt(8) lgkmcnt(0)");  // B-DMA done; avv in flight
  __builtin_amdgcn_sched_barrier(0);
  __builtin_amdgcn_s_barrier();

#pragma unroll
  for (int t = 0; t < 32; ++t) {
    const int cur = t & 1, nxt = cur ^ 1;
    // issue B-DMA for t+1 into free buffer
    if (t + 1 < 32) STAGE_B(t + 1, nxt);
    __builtin_amdgcn_sched_barrier(0);
    // B frags (reused across all 8 row-frags)
    bf16x8 bfr0 = *(const bf16x8*)&ldsB[cur][wave * 64 + lrow][acs];
    bf16x8 bfr1 = *(const bf16x8*)&ldsB[cur][wave * 64 + 16 + lrow][acs];
    bf16x8 bfr2 = *(const bf16x8*)&ldsB[cur][wave * 64 + 32 + lrow][acs];
    bf16x8 bfr3 = *(const bf16x8*)&ldsB[cur][wave * 64 + 48 + lrow][acs];
    // stage A(t+1): cvt regs (loaded 2 tiles ago) -> LDS[nxt]
    if (t + 1 < 32) {
#pragma unroll
      for (int p = 0; p < 4; ++p)
        *(int2*)&ldsA[nxt][arow + 32 * p][awz] = cvt4(avv[(t + 1) & 1][p]);
    }
    // refill freed slot with A fp32 for t+3 (2-tile cover > HBM latency)
    if (t + 3 < 32) {
#pragma unroll
      for (int p = 0; p < 4; ++p)
        avv[(t + 1) & 1][p] =
            *(const float4*)(aptrA + (size_t)p * 32768 + (t + 3) * 32);
    }
    // MFMA 8x4 (A frags interleaved by compiler with fine lgkm waits)
    __builtin_amdgcn_s_setprio(1);
#pragma unroll
    for (int i = 0; i < 8; ++i) {
      const bf16x8 af = *(const bf16x8*)&ldsA[cur][i * 16 + lrow][acs];
      acc[i][0] = __builtin_amdgcn_mfma_f32_16x16x32_bf16(af, bfr0, acc[i][0], 0, 0, 0);
      acc[i][1] = __builtin_amdgcn_mfma_f32_16x16x32_bf16(af, bfr1, acc[i][1], 0, 0, 0);
      acc[i][2] = __builtin_amdgcn_mfma_f32_16x16x32_bf16(af, bfr2, acc[i][2], 0, 0, 0);
      acc[i][3] = __builtin_amdgcn_mfma_f32_16x16x32_bf16(af, bfr3, acc[i][3], 0, 0, 0);
    }
    __builtin_amdgcn_s_setprio(0);
    // tile boundary: B-DMA(t+1) + own ds ops must be done; avv stays in flight
    __builtin_amdgcn_sched_barrier(0);
    if (t + 3 < 32) {
      asm volatile("s_waitcnt vmcnt(4) lgkmcnt(0)");
    } else {
      asm volatile("s_waitcnt vmcnt(0) lgkmcnt(0)");
    }
    __builtin_amdgcn_sched_barrier(0);
    __builtin_amdgcn_s_barrier();
  }

  // ---- epilogue: score partial per row over this 256-col block ----
  float hbv[4], wpv[4];
#pragma unroll
  for (int j = 0; j < 4; ++j) {
    const int idx = wave * 64 + j * 16 + lrow;
    hbv[j] = hbl[idx];
    wpv[j] = wpl[idx];
  }
  float rs[8][4];
#pragma unroll
  for (int i = 0; i < 8; ++i) {
#pragma unroll
    for (int r = 0; r < 4; ++r) {
      float s = 0.f;
#pragma unroll
      for (int j = 0; j < 4; ++j)
        s += tanh_fast(acc[i][j][r] + hbv[j]) * wpv[j];
      s += __shfl_xor(s, 8);
      s += __shfl_xor(s, 4);
      s += __shfl_xor(s, 2);
      s += __shfl_xor(s, 1);
      rs[i][r] = s;
    }
  }
  if (wave != 0 && lrow == 0) {
#pragma unroll
    for (int i = 0; i < 8; ++i)
#pragma unroll
      for (int r = 0; r < 4; ++r)
        sred[wave - 1][i * 16 + quad * 4 + r] = rs[i][r];
  }
  __syncthreads();
  if (wave == 0 && lrow == 0) {
#pragma unroll
    for (int i = 0; i < 8; ++i)
#pragma unroll
      for (int r = 0; r < 4; ++r) {
        const int ro = i * 16 + quad * 4 + r;
        score_p[(size_t)blockIdx.x * 32768 + row0 + ro] =
            rs[i][r] + sred[0][ro] + sred[1][ro] + sred[2][ro];
      }
  }
}

// -------- softmax over L per b (sums 4 partials); also zeroes out[b][:] --------
__global__ __launch_bounds__(256) void softmax_kernel(
    const float* __restrict__ score_p, float* __restrict__ w,
    float* __restrict__ out) {
  const int b = blockIdx.x, tid = threadIdx.x;
  const int lane = tid & 63, wv = tid >> 6;
  __shared__ float sm[4], ss[4];
  float v[4];
  float mx = -1e30f;
#pragma unroll
  for (int i = 0; i < 4; ++i) {
    const int idx = b * 1024 + i * 256 + tid;
    out[idx] = 0.f;  // d_out poisoned; context atomicAdds later
    float s = 0.f;
#pragma unroll
    for (int p = 0; p < 4; ++p) s += score_p[p * 32768 + idx];
    v[i] = s;
    mx = fmaxf(mx, s);
  }
#pragma unroll
  for (int off = 32; off; off >>= 1) mx = fmaxf(mx, __shfl_xor(mx, off));
  if (lane == 0) sm[wv] = mx;
  __syncthreads();
  mx = fmaxf(fmaxf(sm[0], sm[1]), fmaxf(sm[2], sm[3]));
  float sum = 0.f;
#pragma unroll
  for (int i = 0; i < 4; ++i) {
    v[i] = __expf(v[i] - mx);
    sum += v[i];
  }
#pragma unroll
  for (int off = 32; off; off >>= 1) sum += __shfl_xor(sum, off);
  if (lane == 0) ss[wv] = sum;
  __syncthreads();
  const float inv = 1.f / (ss[0] + ss[1] + ss[2] + ss[3]);
#pragma unroll
  for (int i = 0; i < 4; ++i) w[b * 1024 + i * 256 + tid] = v[i] * inv;
}

// -------- out[b][f] += sum_{l in 64-chunk} w[b][l]*feat[b][l][f] (fp32) --------
__global__ __launch_bounds__(256) void context_kernel(
    const float* __restrict__ w, const float* __restrict__ feat,
    float* __restrict__ out) {
  const int b = blockIdx.y;
  const int l0 = blockIdx.x * 64;
  const int f0 = threadIdx.x * 4;
  __shared__ float wl[64];
  if (threadIdx.x < 64) wl[threadIdx.x] = w[b * 1024 + l0 + threadIdx.x];
  __syncthreads();
  const float* fb = feat + (size_t)b * 1048576 + (size_t)l0 * 1024 + f0;
  float a0 = 0.f, a1 = 0.f, a2 = 0.f, a3 = 0.f;
#pragma unroll 8
  for (int l = 0; l < 64; ++l) {
    float4 v = *(const float4*)(fb + (size_t)l * 1024);
    const float wv = wl[l];
    a0 += wv * v.x;
    a1 += wv * v.y;
    a2 += wv * v.z;
    a3 += wv * v.w;
  }
  float* dst = out + b * 1024 + f0;
  atomicAdd(dst + 0, a0);
  atomicAdd(dst + 1, a1);
  atomicAdd(dst + 2, a2);
  atomicAdd(dst + 3, a3);
}

extern "C" void kernel_launch(void* const* d_in, const int* in_sizes, int n_in,
                              void* d_out, int out_size, void* d_ws, size_t ws_size,
                              hipStream_t stream) {
  const float* feat   = (const float*)d_in[0];
  const float* hidden = (const float*)d_in[1];
  const float* W1     = (const float*)d_in[2];
  const float* b1     = (const float*)d_in[3];
  const float* W2     = (const float*)d_in[4];
  const float* b2     = (const float*)d_in[5];
  const float* Wp     = (const float*)d_in[6];
  float* out = (float*)d_out;

  char* ws = (char*)d_ws;
  ushort* w1t    = (ushort*)ws;              // 2 MB
  float* score_p = (float*)(ws + 2097152);   // 512 KB [4][32768]
  float* h2p     = (float*)(ws + 3145728);   // 1 MB [8][32768]
  float* wts     = (float*)(ws + 4194304);   // 128 KB

  prep_kernel<<<1280, 256, 0, stream>>>(W1, w1t, hidden, W2, b2, h2p);
  gemm_score_kernel<<<dim3(4, 256), 256, 0, stream>>>(feat, w1t, b1, h2p, Wp,
                                                      score_p);
  softmax_kernel<<<32, 256, 0, stream>>>(score_p, wts, out);
  context_kernel<<<dim3(16, 32), 256, 0, stream>>>(wts, feat, out);
}